// Round 13
// baseline (111.301 us; speedup 1.0000x reference)
//
#include <hip/hip_runtime.h>

#define SEQ_N 1024
#define BATCH 64
#define NM    2            // matrices per block (waves 0-3 -> m0, 4-7 -> m1)
#define NW    4            // waves per matrix
#define RPL   4            // rows per lane: 4 waves * 64 lanes * 4 = 1024 rows
#define KSL   32           // epoch length (steps between barriers)
#define DELTA 96           // column delay between consecutive waves
#define LAG   33           // DELTA-63: consumer step s reads producer step s-33
#define RINGN 160          // 128 slots + 32 mirror (wrap-free batched reads)
#define PAD_F 352          // front pad: max off = 3*96+63 = 351
#define PAD_B 384          // back pad: max y index 1407

// Wave-wide shift-up-by-1 in one instruction (DPP wave_shr:1, ctrl 0x138).
// bound_ctrl=false -> lane 0 takes `fill` (INF) = top-row boundary for free.
__device__ __forceinline__ float wave_shr1(float v, float fill) {
    return __int_as_float(__builtin_amdgcn_update_dpp(
        __float_as_int(fill), __float_as_int(v), 0x138, 0xF, 0xF, false));
}

// TWO independent DTW matrices per block (8 waves, 512 threads): each SIMD
// hosts 2 waves from DIFFERENT matrices, so one wave's dependency-chain gaps
// (~80cy/step measured at 1 wave/SIMD, per-SIMD VALUBusy stuck at 46%) are
// filled by the other wave's issue. Identical static schedule for both
// halves keeps the shared __syncthreads balanced.
//
// Per matrix: 4 waves, barrier per 32-step epoch (43 barriers). Wave w owns
// rows [w*256,+256), lane l rows w*256+4l..+4; lane (w,l) at step s computes
// column j = s - (96w + l). Batched register arrays for ring-read/y-prefetch/
// bottoms (R11 lesson: per-step LDS reads serialize ~120cy; batched ~6cy).
//
// Ring (128 slots, slot = producer step & 127, batched):
//  RAW: consumer reads p at head of epoch floor((p+33)/32) >= E_p+1.
//  WAR: slot p reused at p+128 (E_p+4); last read head of E_p+2.
//  Wrap: rbase = (32E-33)&127 in {95,127,31,63}; only 127 wraps, reading
//    [127..158]; mirror [128..159] = slots 0..31, written by mm==0 epochs.
//
// Corner seed: D[0,0] needs up=0 at (epoch 0, k2=0, th==0); diag_top is then
// restored to INF so cell (0,1) doesn't inherit 0 through the diag path.
__global__ __launch_bounds__(512, 1) void dtw_kernel(const float* __restrict__ x,
                                                     const float* __restrict__ y,
                                                     float* __restrict__ dists) {
    __shared__ float sy_raw[NM][PAD_F + SEQ_N + PAD_B];
    __shared__ float ring[NM][NW - 1][RINGN];

    const int tid = threadIdx.x;
    const int m   = tid >> 8;        // matrix slot 0/1
    const int th  = tid & 255;       // thread id within the matrix group
    const int w   = th >> 6;         // wave id 0..3 within the matrix
    const int l   = tid & 63;        // lane id
    const int b   = blockIdx.x * NM + m;
    const float INF = 3.0e37f;
    const int  off = w * DELTA + l;  // column delay of this lane
    const bool is_ring_l0 = (l == 0) && (w > 0);
    const bool is_seed = (th == 0);

    // zero pads (each half initializes its own matrix's LDS)
    for (int i = th; i < PAD_F; i += 256) sy_raw[m][i] = 0.0f;
    for (int i = th; i < PAD_B; i += 256) sy_raw[m][PAD_F + SEQ_N + i] = 0.0f;
    // stage y (one float4 per thread)
    ((float4*)(sy_raw[m] + PAD_F))[th] = ((const float4*)(y + b * SEQ_N))[th];
    // this lane's 4 x-rows (one float4)
    const float4 xv = *((const float4*)(x + b * SEQ_N + w * 256 + l * RPL));
    const float xr0 = xv.x, xr1 = xv.y, xr2 = xv.z, xr3 = xv.w;
    __syncthreads();

    const float* const yp = sy_raw[m] + PAD_F - off;   // yp[s] == y[s - off]

    float c0 = INF, c1 = INF, c2 = INF, c3 = INF;   // col[0..3]
    float diag_top = INF, bottom = INF;
    float yA[KSL], yB[KSL], rb[KSL], bt[KSL];

    // prologue: y values for epoch 0
    #pragma unroll
    for (int k = 0; k < KSL; ++k) yA[k] = yp[k];

// One 32-step epoch. YU = y regs for this epoch, YF = filled with next
// epoch's y. Ring reads batched right after the barrier; bottoms collected
// in bt[] and written (plus mirror on mm==0 epochs) at epoch end.
#define EPOCH(MASKED, FIRST, S0, YU, YF)                                     \
  {                                                                          \
    __syncthreads();                                                         \
    if (w > 0) {                                                             \
      int rbase = ((S0) & 127) + 95; if (rbase >= 128) rbase -= 128;         \
      const float* rp = ring[m][w - 1] + rbase;                              \
      _Pragma("unroll")                                                      \
      for (int k2 = 0; k2 < KSL; ++k2) rb[k2] = rp[k2];                      \
    } else {                                                                 \
      _Pragma("unroll")                                                      \
      for (int k2 = 0; k2 < KSL; ++k2) rb[k2] = INF;                         \
    }                                                                        \
    _Pragma("unroll")                                                        \
    for (int k2 = 0; k2 < KSL; ++k2) YF[k2] = yp[(S0) + KSL + k2];           \
    _Pragma("unroll")                                                        \
    for (int k2 = 0; k2 < KSL; ++k2) {                                       \
      const float up_dpp = wave_shr1(bottom, INF);                           \
      float upv = is_ring_l0 ? rb[k2] : up_dpp;                              \
      if ((FIRST) && k2 == 0 && is_seed) upv = 0.0f;  /* seed D[0,0]=d */    \
      const float yj = YU[k2];                                               \
      bool act = true;                                                       \
      if (MASKED) act = ((unsigned)((S0) + k2 - off) < (unsigned)SEQ_N);     \
      if (act) {                                                             \
        const float d0 = xr0 - yj, d1 = xr1 - yj,                            \
                    d2 = xr2 - yj, d3 = xr3 - yj;                            \
        const float t0 = diag_top + fabsf(d0);                               \
        const float t1 = c0 + fabsf(d1);                                     \
        const float t2 = c1 + fabsf(d2);                                     \
        const float t3 = c2 + fabsf(d3);                                     \
        float v = upv;                                                       \
        v = fminf(fminf(t0, c0), v) + fabsf(d0); c0 = v;                     \
        v = fminf(fminf(t1, c1), v) + fabsf(d1); c1 = v;                     \
        v = fminf(fminf(t2, c2), v) + fabsf(d2); c2 = v;                     \
        v = fminf(fminf(t3, c3), v) + fabsf(d3); c3 = v;                     \
        diag_top = upv; bottom = v;                                          \
      }                                                                      \
      if ((FIRST) && k2 == 0 && is_seed) diag_top = INF; /* un-contaminate */\
      bt[k2] = bottom;                                                       \
    }                                                                        \
    if (w < NW - 1 && l == 63) {                                             \
      const int mm = (S0) & 127;                                             \
      float* wp = ring[m][w] + mm;                                           \
      _Pragma("unroll")                                                      \
      for (int k2 = 0; k2 < KSL; ++k2) wp[k2] = bt[k2];                      \
      if (mm == 0) {                                                         \
        _Pragma("unroll")                                                    \
        for (int k2 = 0; k2 < KSL; ++k2) ring[m][w][128 + k2] = bt[k2];      \
      }                                                                      \
    }                                                                        \
  }

    // epoch 0: carries the corner seed
    EPOCH(true, true, 0, yA, yB);
    int s0 = 32;
    // epochs 1..10: ramp-up (max off = 351; all-active from step 351)
    for (int it = 0; it < 5; ++it) {
        EPOCH(true, false, s0, yB, yA);
        EPOCH(true, false, s0 + 32, yA, yB);
        s0 += 64;
    }
    // epochs 11..30: steady (S0 in [352, 960]; S0+31 <= 991 <= 1023)
    for (int it = 0; it < 10; ++it) {
        EPOCH(false, false, s0, yB, yA);
        EPOCH(false, false, s0 + 32, yA, yB);
        s0 += 64;
    }
    // epochs 31..42: ramp-down (last active step = 1023 + 351 = 1374)
    for (int it = 0; it < 6; ++it) {
        EPOCH(true, false, s0, yB, yA);
        EPOCH(true, false, s0 + 32, yA, yB);
        s0 += 64;
    }
#undef EPOCH

    // D[1023,1023] of matrix m lives in its wave-3 lane-63 c3
    if (th == 255) dists[b] = c3 * (1.0f / (2.0f * (float)SEQ_N));
}

// Mean over the 64 per-batch distances -> single float output.
__global__ void dtw_reduce_kernel(const float* __restrict__ dists,
                                  float* __restrict__ out) {
    float v = dists[threadIdx.x] * (1.0f / (float)BATCH);
    #pragma unroll
    for (int o = 32; o > 0; o >>= 1) v += __shfl_down(v, o);
    if (threadIdx.x == 0) out[0] = v;
}

extern "C" void kernel_launch(void* const* d_in, const int* in_sizes, int n_in,
                              void* d_out, int out_size, void* d_ws, size_t ws_size,
                              hipStream_t stream) {
    const float* x = (const float*)d_in[0];
    const float* y = (const float*)d_in[1];
    float* out = (float*)d_out;
    float* dists = (float*)d_ws;  // 64 floats of scratch

    dtw_kernel<<<BATCH / NM, 512, 0, stream>>>(x, y, dists);
    dtw_reduce_kernel<<<1, BATCH, 0, stream>>>(dists, out);
}

// Round 14
// 93.581 us; speedup vs baseline: 1.1894x; 1.1894x over previous
//
#include <hip/hip_runtime.h>

#define SEQ_N 1024
#define BATCH 64
#define NW    4            // waves per block (per batch element)
#define KSL   16           // epoch length in STEPS (1 step = 2 columns)
#define DELTA 80           // wave delay in steps (63 lane skew + LAG 17)
#define RINGN 80           // float2 ring: 64 slots + 16 mirror
#define PAD_F2 304         // float2 front pad: max off_s = 3*80+63 = 303
#define PAD_B2 320         // float2 back pad: max yp2 index 831 -> 831-511=320
#define NPAIR 512          // column pairs per lane

// Wave-wide shift-up-by-1 in one instruction (DPP wave_shr:1, ctrl 0x138).
// bound_ctrl=false -> lane 0 takes `fill` (INF) = top-row boundary for free.
__device__ __forceinline__ float wave_shr1(float v, float fill) {
    return __int_as_float(__builtin_amdgcn_update_dpp(
        __float_as_int(fill), __float_as_int(v), 0x138, 0xF, 0xF, false));
}

// 2-COLUMN TILES: lane (w,l) at step s computes columns {2(s-off), 2(s-off)+1}
// for its 4 rows (off = 80w + l, in steps). 8 cells/step amortize the per-step
// overhead (2 DPP + cndmask + 1 ds_read_b64 + bookkeeping) that cost R12 ~13
// extra instr over the 16 cell-ops; steps drop 1376 -> 815.
//
// Handoff: lane l-1 at step s-1 computed exactly the columns lane l needs at
// step s -> upA,upB via 2 DPPs. diagA[0] = previous step's upB (register);
// diagB[0] = upA (captured BEFORE the corner seed overwrites upA).
// Ring: float2 (botA,botB) per producer step, slot = step & 63, batched reads
// at epoch head / writes at epoch end -- identical RAW/WAR/mirror proof as the
// verified KSL=16 kernel (consumer reads p=s-17: >=1 barrier; slot reuse at
// p+64: >=2 barriers after last read; rbase in {47,63,15,31}, only 63 wraps
// into mirror [64..79], written by the mm==0 producer epochs).
__global__ __launch_bounds__(256, 1) void dtw_kernel(const float* __restrict__ x,
                                                     const float* __restrict__ y,
                                                     float* __restrict__ dists) {
    __shared__ float2 sy2[PAD_F2 + NPAIR + PAD_B2];
    __shared__ float2 ring[NW - 1][RINGN];

    const int b   = blockIdx.x;
    const int tid = threadIdx.x;
    const int w   = tid >> 6;        // wave id 0..3
    const int l   = tid & 63;        // lane id
    const float INF = 3.0e37f;
    const int  off = w * DELTA + l;  // step delay of this lane
    const bool is_ring_l0 = (l == 0) && (w > 0);
    const bool is_seed = (tid == 0);

    // zero pads
    for (int i = tid; i < PAD_F2; i += 256) sy2[i] = make_float2(0.f, 0.f);
    for (int i = tid; i < PAD_B2; i += 256) sy2[PAD_F2 + NPAIR + i] = make_float2(0.f, 0.f);
    // stage y: 256 threads x float4 = 1024 floats (PAD_F2*8 bytes is 16B-aligned)
    ((float4*)(sy2 + PAD_F2))[tid] = ((const float4*)(y + b * SEQ_N))[tid];
    // this lane's 4 x-rows (one float4)
    const float4 xv = *((const float4*)(x + b * SEQ_N + w * 256 + l * 4));
    const float xr0 = xv.x, xr1 = xv.y, xr2 = xv.z, xr3 = xv.w;
    __syncthreads();

    const float2* const yp2 = sy2 + PAD_F2 - off;   // yp2[s] == y-pair for step s

    float c0 = INF, c1 = INF, c2 = INF, c3 = INF;   // D[r, last jB]
    float diag_top = INF;                           // prev step's upB
    float botA = INF, botB = INF;                   // row-3 values, exported
    float2 yA[KSL], yB[KSL], rb[KSL], bt[KSL];

    #pragma unroll
    for (int k = 0; k < KSL; ++k) yA[k] = yp2[k];
    #pragma unroll
    for (int k = 0; k < KSL; ++k) rb[k] = make_float2(INF, INF);

#define EPOCH(MASKED, FIRST, S0, YU, YF)                                     \
  {                                                                          \
    __syncthreads();                                                         \
    if (w > 0) {                                                             \
      int rbase = ((S0) & 63) + 47; if (rbase >= 64) rbase -= 64;            \
      const float2* rp = ring[w - 1] + rbase;                                \
      _Pragma("unroll")                                                      \
      for (int k2 = 0; k2 < KSL; ++k2) rb[k2] = rp[k2];                      \
    }                                                                        \
    _Pragma("unroll")                                                        \
    for (int k2 = 0; k2 < KSL; ++k2) YF[k2] = yp2[(S0) + KSL + k2];          \
    _Pragma("unroll")                                                        \
    for (int k2 = 0; k2 < KSL; ++k2) {                                       \
      float upA = wave_shr1(botA, INF);                                      \
      float upB = wave_shr1(botB, INF);                                      \
      if (is_ring_l0) { upA = rb[k2].x; upB = rb[k2].y; }                    \
      const float dgB0 = upA;            /* diag for colB row0 (pre-seed) */ \
      if ((FIRST) && k2 == 0 && is_seed) upA = 0.0f;  /* D[0,0] = d */       \
      const float2 yv = YU[k2];                                              \
      bool act = true;                                                       \
      if (MASKED) act = ((unsigned)((S0) + k2 - off) < (unsigned)NPAIR);     \
      if (act) {                                                             \
        const float dA0 = xr0 - yv.x, dA1 = xr1 - yv.x,                      \
                    dA2 = xr2 - yv.x, dA3 = xr3 - yv.x;                      \
        const float dB0 = xr0 - yv.y, dB1 = xr1 - yv.y,                      \
                    dB2 = xr2 - yv.y, dB3 = xr3 - yv.y;                      \
        const float tA0 = diag_top + fabsf(dA0);                             \
        const float tA1 = c0 + fabsf(dA1);                                   \
        const float tA2 = c1 + fabsf(dA2);                                   \
        const float tA3 = c2 + fabsf(dA3);                                   \
        const float a0 = fminf(fminf(tA0, c0), upA) + fabsf(dA0);            \
        const float a1 = fminf(fminf(tA1, c1), a0) + fabsf(dA1);             \
        const float a2 = fminf(fminf(tA2, c2), a1) + fabsf(dA2);             \
        const float a3 = fminf(fminf(tA3, c3), a2) + fabsf(dA3);             \
        const float tB0 = dgB0 + fabsf(dB0);                                 \
        const float tB1 = a0 + fabsf(dB1);                                   \
        const float tB2 = a1 + fabsf(dB2);                                   \
        const float tB3 = a2 + fabsf(dB3);                                   \
        const float b0 = fminf(fminf(tB0, a0), upB) + fabsf(dB0);            \
        const float b1 = fminf(fminf(tB1, a1), b0) + fabsf(dB1);             \
        const float b2 = fminf(fminf(tB2, a2), b1) + fabsf(dB2);             \
        const float b3 = fminf(fminf(tB3, a3), b2) + fabsf(dB3);             \
        c0 = b0; c1 = b1; c2 = b2; c3 = b3;                                  \
        diag_top = upB; botA = a3; botB = b3;                                \
      }                                                                      \
      bt[k2].x = botA; bt[k2].y = botB;                                      \
    }                                                                        \
    if (w < NW - 1 && l == 63) {                                             \
      const int mm = (S0) & 63;                                              \
      float2* wp = ring[w] + mm;                                             \
      _Pragma("unroll")                                                      \
      for (int k2 = 0; k2 < KSL; ++k2) wp[k2] = bt[k2];                      \
      if (mm == 0) {                                                         \
        _Pragma("unroll")                                                    \
        for (int k2 = 0; k2 < KSL; ++k2) ring[w][64 + k2] = bt[k2];          \
      }                                                                      \
    }                                                                        \
  }

    // 51 epochs of 16 steps (steps 0..815; last active step = 303+511 = 814).
    EPOCH(true, true, 0, yA, yB);                       // e0 (corner seed)
    int s0 = 16;
    for (int it = 0; it < 9; ++it) {                    // e1..e18 ramp-up
        EPOCH(true, false, s0, yB, yA);
        EPOCH(true, false, s0 + 16, yA, yB);
        s0 += 32;
    }
    for (int it = 0; it < 6; ++it) {                    // e19..e30 steady
        EPOCH(false, false, s0, yB, yA);                // [304,511] all-active
        EPOCH(false, false, s0 + 16, yA, yB);
        s0 += 32;
    }
    EPOCH(false, false, s0, yB, yA); s0 += 16;          // e31 steady (496..511)
    for (int it = 0; it < 9; ++it) {                    // e32..e49 ramp-down
        EPOCH(true, false, s0, yA, yB);
        EPOCH(true, false, s0 + 16, yB, yA);
        s0 += 32;
    }
    EPOCH(true, false, s0, yA, yB);                     // e50 (800..815)
#undef EPOCH

    // D[1023,1023]: wave 3 lane 63, step 814 -> cols {1022,1023}, c3 = b3.
    if (tid == 255) dists[b] = c3 * (1.0f / (2.0f * (float)SEQ_N));
}

// Mean over the 64 per-batch distances -> single float output.
__global__ void dtw_reduce_kernel(const float* __restrict__ dists,
                                  float* __restrict__ out) {
    float v = dists[threadIdx.x] * (1.0f / (float)BATCH);
    #pragma unroll
    for (int o = 32; o > 0; o >>= 1) v += __shfl_down(v, o);
    if (threadIdx.x == 0) out[0] = v;
}

extern "C" void kernel_launch(void* const* d_in, const int* in_sizes, int n_in,
                              void* d_out, int out_size, void* d_ws, size_t ws_size,
                              hipStream_t stream) {
    const float* x = (const float*)d_in[0];
    const float* y = (const float*)d_in[1];
    float* out = (float*)d_out;
    float* dists = (float*)d_ws;  // 64 floats of scratch

    dtw_kernel<<<BATCH, 256, 0, stream>>>(x, y, dists);
    dtw_reduce_kernel<<<1, BATCH, 0, stream>>>(dists, out);
}

// Round 15
// 85.982 us; speedup vs baseline: 1.2945x; 1.0884x over previous
//
#include <hip/hip_runtime.h>

#define SEQ_N 1024
#define BATCH 64
#define NW    4            // waves per sweep
#define KSL   32           // epoch length (steps between barriers)
#define DELTA 96           // column delay between consecutive waves
#define RINGN 160          // 128 slots + 32 mirror (wrap-free batched reads)
#define PAD_F 352          // front pad: max off = 3*96+63 = 351
#define PAD_B 384          // back pad: max yp index 895 -> 352+895 = 1247
#define NPAIR 512          // columns per sweep (half matrix)
#define SYN   (PAD_F + NPAIR + PAD_B)

// Wave-wide shift-up-by-1 in one instruction (DPP wave_shr:1, ctrl 0x138).
// bound_ctrl=false -> lane 0 takes `fill` = top-row boundary for free.
__device__ __forceinline__ float wave_shr1(float v, float fill) {
    return __int_as_float(__builtin_amdgcn_update_dpp(
        __float_as_int(fill), __float_as_int(v), 0x138, 0xF, 0xF, false));
}

// BIDIRECTIONAL DTW: a path's j is non-decreasing, so it crosses 511->512
// exactly once (h or diag step). Blocks 0..63: forward F over cols 0..511.
// Blocks 64..127: backward DP on reversed sequences over cols 512..1023,
// carrying P = B + d (B excludes own-cell cost). Stitch (separate kernel):
//   D = min_i [ F[i,511] + min( P[i,512], P[i+1,512] + d[i+1,512] ) ].
// Each sweep: 512 cols -> last active step 511+351=862, 27 epochs (vs 43).
// Epoch/ring machinery identical to the verified KSL=32/DELTA=96 kernel:
//   RAW: consumer reads p=s-33 at epoch head, >= 1 barrier after write.
//   WAR: slot p reused at p+128 (4 epochs), >= 2 barriers after last read.
//   Wrap: rbase in {95,127,31,63}; only 127 wraps into mirror [128..159],
//   written by the mm==0 producer epochs.
// Backward cell (reversed coords p=1023-i, q=1023-j, B'[0,0]=0 seed):
//   B = min3( diagP + |diagD|, upP, leftP=cP[r] );  newP = B + |x'-y'|
// where (upP,upD) = row-above's (P, signed diff) via 2 DPPs / float2 ring;
// diag regs hold the previous step's up pair. Verified on 2x2 by hand.
__global__ __launch_bounds__(256, 1) void dtw_sweep_kernel(const float* __restrict__ x,
                                                           const float* __restrict__ y,
                                                           float* __restrict__ wsF,
                                                           float* __restrict__ wsP) {
    __shared__ float  sy_raw[SYN];
    __shared__ float  ringF[NW - 1][RINGN];
    __shared__ float2 ringB[NW - 1][RINGN];

    const int bid = blockIdx.x;
    const int dir = bid >> 6;        // 0 = forward, 1 = backward
    const int b   = bid & 63;
    const int tid = threadIdx.x;
    const int w   = tid >> 6;
    const int l   = tid & 63;
    const float INF = 3.0e37f;
    const int  off = w * DELTA + l;
    const bool is_ring_l0 = (l == 0) && (w > 0);
    const bool is_seed = (tid == 0);
    const int  r0 = w * 256 + l * 4;   // first owned row (fwd: i-rows, bwd: p-rows)

    // zero pads
    for (int i = tid; i < PAD_F; i += 256) sy_raw[i] = 0.0f;
    for (int i = tid; i < PAD_B; i += 256) sy_raw[PAD_F + NPAIR + i] = 0.0f;
    // stage y columns (512 floats): fwd y[0..511]; bwd y'[q]=y[1023-q]
    if (tid < NPAIR / 4) {
        if (dir == 0) {
            ((float4*)(sy_raw + PAD_F))[tid] = ((const float4*)(y + b * SEQ_N))[tid];
        } else {
            const float4 v = *((const float4*)(y + b * SEQ_N + 1020 - 4 * tid));
            ((float4*)(sy_raw + PAD_F))[tid] = make_float4(v.w, v.z, v.y, v.x);
        }
    }
    // x fragment: fwd rows r0..r0+3; bwd x'[p]=x[1023-p]
    float xr0, xr1, xr2, xr3;
    if (dir == 0) {
        const float4 v = *((const float4*)(x + b * SEQ_N + r0));
        xr0 = v.x; xr1 = v.y; xr2 = v.z; xr3 = v.w;
    } else {
        const float4 v = *((const float4*)(x + b * SEQ_N + 1020 - r0));
        xr0 = v.w; xr1 = v.z; xr2 = v.y; xr3 = v.x;
    }
    __syncthreads();

    const float* const yp = sy_raw + PAD_F - off;   // yp[s] == y-col for step s

    if (dir == 0) {
        // ---------------- FORWARD (verified R12 structure) ----------------
        float c0 = INF, c1 = INF, c2 = INF, c3 = INF;
        float diag_top = INF, bottom = INF;
        float yA[KSL], yB[KSL], rb[KSL], bt[KSL];
        #pragma unroll
        for (int k = 0; k < KSL; ++k) yA[k] = yp[k];

#define FEPOCH(MASKED, FIRST, S0, YU, YF)                                    \
  {                                                                          \
    __syncthreads();                                                         \
    if (w > 0) {                                                             \
      int rbase = ((S0) & 127) + 95; if (rbase >= 128) rbase -= 128;         \
      const float* rp = ringF[w - 1] + rbase;                                \
      _Pragma("unroll")                                                      \
      for (int k2 = 0; k2 < KSL; ++k2) rb[k2] = rp[k2];                      \
    } else {                                                                 \
      _Pragma("unroll")                                                      \
      for (int k2 = 0; k2 < KSL; ++k2) rb[k2] = INF;                         \
    }                                                                        \
    _Pragma("unroll")                                                        \
    for (int k2 = 0; k2 < KSL; ++k2) YF[k2] = yp[(S0) + KSL + k2];           \
    _Pragma("unroll")                                                        \
    for (int k2 = 0; k2 < KSL; ++k2) {                                       \
      const float up_dpp = wave_shr1(bottom, INF);                           \
      float upv = is_ring_l0 ? rb[k2] : up_dpp;                              \
      if ((FIRST) && k2 == 0 && is_seed) upv = 0.0f;                         \
      const float yj = YU[k2];                                               \
      bool act = true;                                                       \
      if (MASKED) act = ((unsigned)((S0) + k2 - off) < (unsigned)NPAIR);     \
      if (act) {                                                             \
        const float d0 = xr0 - yj, d1 = xr1 - yj,                            \
                    d2 = xr2 - yj, d3 = xr3 - yj;                            \
        const float t0 = diag_top + fabsf(d0);                               \
        const float t1 = c0 + fabsf(d1);                                     \
        const float t2 = c1 + fabsf(d2);                                     \
        const float t3 = c2 + fabsf(d3);                                     \
        float v = upv;                                                       \
        v = fminf(fminf(t0, c0), v) + fabsf(d0); c0 = v;                     \
        v = fminf(fminf(t1, c1), v) + fabsf(d1); c1 = v;                     \
        v = fminf(fminf(t2, c2), v) + fabsf(d2); c2 = v;                     \
        v = fminf(fminf(t3, c3), v) + fabsf(d3); c3 = v;                     \
        diag_top = upv; bottom = v;                                          \
      }                                                                      \
      if ((FIRST) && k2 == 0 && is_seed) diag_top = INF;                     \
      bt[k2] = bottom;                                                       \
    }                                                                        \
    if (w < NW - 1 && l == 63) {                                             \
      const int mm = (S0) & 127;                                             \
      float* wp = ringF[w] + mm;                                             \
      _Pragma("unroll")                                                      \
      for (int k2 = 0; k2 < KSL; ++k2) wp[k2] = bt[k2];                      \
      if (mm == 0) {                                                         \
        _Pragma("unroll")                                                    \
        for (int k2 = 0; k2 < KSL; ++k2) ringF[w][128 + k2] = bt[k2];        \
      }                                                                      \
    }                                                                        \
  }
        // 27 epochs; parity: even epochs read yA/fill yB, odd read yB/fill yA
        FEPOCH(true, true, 0, yA, yB);
        int s0 = 32;
        for (int it = 0; it < 5; ++it) {                  // e1..e10 ramp-up
            FEPOCH(true, false, s0, yB, yA);
            FEPOCH(true, false, s0 + 32, yA, yB);
            s0 += 64;
        }
        for (int it = 0; it < 2; ++it) {                  // e11..e14 steady
            FEPOCH(false, false, s0, yB, yA);
            FEPOCH(false, false, s0 + 32, yA, yB);
            s0 += 64;
        }
        FEPOCH(false, false, s0, yB, yA); s0 += 32;       // e15 steady
        for (int it = 0; it < 5; ++it) {                  // e16..e25 ramp-down
            FEPOCH(true, false, s0, yA, yB);
            FEPOCH(true, false, s0 + 32, yB, yA);
            s0 += 64;
        }
        FEPOCH(true, false, s0, yA, yB);                  // e26
#undef FEPOCH
        // export F[r, 511] for owned rows
        *((float4*)(wsF + b * SEQ_N + r0)) = make_float4(c0, c1, c2, c3);
    } else {
        // ---------------- BACKWARD (reversed, P = B + d) ----------------
        float cP0 = INF, cP1 = INF, cP2 = INF, cP3 = INF;
        float cD0 = 0.f, cD1 = 0.f, cD2 = 0.f, cD3 = 0.f;
        float diag_P = INF, diag_D = 0.f;
        float botP = INF, botD = 0.f;
        float yA[KSL], yB[KSL];
        float2 rb2[KSL], bt2[KSL];
        #pragma unroll
        for (int k = 0; k < KSL; ++k) yA[k] = yp[k];

#define BEPOCH(MASKED, FIRST, S0, YU, YF)                                    \
  {                                                                          \
    __syncthreads();                                                         \
    if (w > 0) {                                                             \
      int rbase = ((S0) & 127) + 95; if (rbase >= 128) rbase -= 128;         \
      const float2* rp = ringB[w - 1] + rbase;                               \
      _Pragma("unroll")                                                      \
      for (int k2 = 0; k2 < KSL; ++k2) rb2[k2] = rp[k2];                     \
    } else {                                                                 \
      _Pragma("unroll")                                                      \
      for (int k2 = 0; k2 < KSL; ++k2) rb2[k2] = make_float2(INF, 0.f);      \
    }                                                                        \
    _Pragma("unroll")                                                        \
    for (int k2 = 0; k2 < KSL; ++k2) YF[k2] = yp[(S0) + KSL + k2];           \
    _Pragma("unroll")                                                        \
    for (int k2 = 0; k2 < KSL; ++k2) {                                       \
      float upP = wave_shr1(botP, INF);                                      \
      float upD = wave_shr1(botD, 0.0f);                                     \
      if (is_ring_l0) { upP = rb2[k2].x; upD = rb2[k2].y; }                  \
      if ((FIRST) && k2 == 0 && is_seed) upP = 0.0f;  /* B'[0,0] = 0 */      \
      const float yj = YU[k2];                                               \
      bool act = true;                                                       \
      if (MASKED) act = ((unsigned)((S0) + k2 - off) < (unsigned)NPAIR);     \
      if (act) {                                                             \
        const float f0 = xr0 - yj, f1 = xr1 - yj,                            \
                    f2 = xr2 - yj, f3 = xr3 - yj;                            \
        const float t0 = diag_P + fabsf(diag_D);                             \
        const float t1 = cP0 + fabsf(cD0);                                   \
        const float t2 = cP1 + fabsf(cD1);                                   \
        const float t3 = cP2 + fabsf(cD2);                                   \
        float Bv = fminf(fminf(t0, upP), cP0);                               \
        const float P0 = Bv + fabsf(f0);                                     \
        Bv = fminf(fminf(t1, P0), cP1); const float P1 = Bv + fabsf(f1);     \
        Bv = fminf(fminf(t2, P1), cP2); const float P2 = Bv + fabsf(f2);     \
        Bv = fminf(fminf(t3, P2), cP3); const float P3 = Bv + fabsf(f3);     \
        cP0 = P0; cP1 = P1; cP2 = P2; cP3 = P3;                              \
        cD0 = f0; cD1 = f1; cD2 = f2; cD3 = f3;                              \
        diag_P = upP; diag_D = upD;                                          \
        botP = P3; botD = f3;                                                \
      }                                                                      \
      if ((FIRST) && k2 == 0 && is_seed) diag_P = INF; /* un-contaminate */  \
      bt2[k2] = make_float2(botP, botD);                                     \
    }                                                                        \
    if (w < NW - 1 && l == 63) {                                             \
      const int mm = (S0) & 127;                                             \
      float2* wp = ringB[w] + mm;                                            \
      _Pragma("unroll")                                                      \
      for (int k2 = 0; k2 < KSL; ++k2) wp[k2] = bt2[k2];                     \
      if (mm == 0) {                                                         \
        _Pragma("unroll")                                                    \
        for (int k2 = 0; k2 < KSL; ++k2) ringB[w][128 + k2] = bt2[k2];       \
      }                                                                      \
    }                                                                        \
  }
        BEPOCH(true, true, 0, yA, yB);
        int s0 = 32;
        for (int it = 0; it < 5; ++it) {                  // e1..e10 ramp-up
            BEPOCH(true, false, s0, yB, yA);
            BEPOCH(true, false, s0 + 32, yA, yB);
            s0 += 64;
        }
        for (int it = 0; it < 2; ++it) {                  // e11..e14 steady
            BEPOCH(false, false, s0, yB, yA);
            BEPOCH(false, false, s0 + 32, yA, yB);
            s0 += 64;
        }
        BEPOCH(false, false, s0, yB, yA); s0 += 32;       // e15 steady
        for (int it = 0; it < 5; ++it) {                  // e16..e25 ramp-down
            BEPOCH(true, false, s0, yA, yB);
            BEPOCH(true, false, s0 + 32, yB, yA);
            s0 += 64;
        }
        BEPOCH(true, false, s0, yA, yB);                  // e26
#undef BEPOCH
        // export P[i,512]: cPk holds P'[r0+k, 511] = P[1023-(r0+k), 512]
        *((float4*)(wsP + b * SEQ_N + 1020 - r0)) = make_float4(cP3, cP2, cP1, cP0);
    }
}

// Stitch: D[b] = min_i [ F[i] + min(P[i], P[i+1] + |x[i+1]-y[512]|) ] / 2048
__global__ void dtw_stitch_kernel(const float* __restrict__ x,
                                  const float* __restrict__ y,
                                  const float* __restrict__ wsF,
                                  const float* __restrict__ wsP,
                                  float* __restrict__ dists) {
    __shared__ float red[4];
    const int b = blockIdx.x, t = threadIdx.x;
    const float INF = 3.0e37f;
    const float y512 = y[b * SEQ_N + 512];
    const float4 Fv = ((const float4*)(wsF + b * SEQ_N))[t];
    const float4 Pv = ((const float4*)(wsP + b * SEQ_N))[t];
    const float Pn4 = (t < 255) ? wsP[b * SEQ_N + 4 * t + 4] : INF;
    const float F[4]  = {Fv.x, Fv.y, Fv.z, Fv.w};
    const float P[4]  = {Pv.x, Pv.y, Pv.z, Pv.w};
    const float Pn[4] = {Pv.y, Pv.z, Pv.w, Pn4};
    float m = INF;
    #pragma unroll
    for (int k = 0; k < 4; ++k) {
        const int i = 4 * t + k;
        const float xn = (i < 1023) ? x[b * SEQ_N + i + 1] : 0.f;
        const float alt = (i < 1023) ? Pn[k] + fabsf(xn - y512) : INF;
        m = fminf(m, F[k] + fminf(P[k], alt));
    }
    #pragma unroll
    for (int o = 32; o > 0; o >>= 1) m = fminf(m, __shfl_down(m, o));
    if ((t & 63) == 0) red[t >> 6] = m;
    __syncthreads();
    if (t == 0)
        dists[b] = fminf(fminf(red[0], red[1]), fminf(red[2], red[3]))
                   * (1.0f / (2.0f * (float)SEQ_N));
}

// Mean over the 64 per-batch distances -> single float output.
__global__ void dtw_reduce_kernel(const float* __restrict__ dists,
                                  float* __restrict__ out) {
    float v = dists[threadIdx.x] * (1.0f / (float)BATCH);
    #pragma unroll
    for (int o = 32; o > 0; o >>= 1) v += __shfl_down(v, o);
    if (threadIdx.x == 0) out[0] = v;
}

extern "C" void kernel_launch(void* const* d_in, const int* in_sizes, int n_in,
                              void* d_out, int out_size, void* d_ws, size_t ws_size,
                              hipStream_t stream) {
    const float* x = (const float*)d_in[0];
    const float* y = (const float*)d_in[1];
    float* out = (float*)d_out;
    float* wsF   = (float*)d_ws;                     // 64*1024 floats
    float* wsP   = wsF + BATCH * SEQ_N;              // 64*1024 floats
    float* dists = wsP + BATCH * SEQ_N;              // 64 floats

    dtw_sweep_kernel<<<2 * BATCH, 256, 0, stream>>>(x, y, wsF, wsP);
    dtw_stitch_kernel<<<BATCH, 256, 0, stream>>>(x, y, wsF, wsP, dists);
    dtw_reduce_kernel<<<1, BATCH, 0, stream>>>(dists, out);
}